// Round 14
// baseline (188.894 us; speedup 1.0000x reference)
//
#include <hip/hip_runtime.h>
#include <math.h>

#define H 16
#define S 2048
#define DM 1024
#define HD 64
// 0.125 (1/sqrt(64)) * log2(e): softmax computed in exp2 domain
#define QSCALE 0.18033688011112042f

typedef __attribute__((ext_vector_type(8))) short short8;
typedef __attribute__((ext_vector_type(4))) float f32x4;
typedef __attribute__((ext_vector_type(4))) unsigned short u16x4;
typedef __attribute__((ext_vector_type(2))) unsigned int uint2v;
#if __has_builtin(__builtin_amdgcn_cvt_pk_bf16_f32)
typedef __attribute__((ext_vector_type(2))) __bf16 bf16x2;
#endif

__device__ __forceinline__ unsigned short f2bf(float f) {
  unsigned int u = __builtin_bit_cast(unsigned int, f);
  u = (u + 0x7fffu + ((u >> 16) & 1u)) >> 16;
  return (unsigned short)u;
}

__device__ __forceinline__ unsigned int pk_bf16(float a, float b) {
#if __has_builtin(__builtin_amdgcn_cvt_pk_bf16_f32)
  bf16x2 r = __builtin_amdgcn_cvt_pk_bf16_f32(a, b);
  return __builtin_bit_cast(unsigned int, r);
#else
  return (unsigned int)f2bf(a) | ((unsigned int)f2bf(b) << 16);
#endif
}

__device__ __forceinline__ float fexp2(float x) {
#if __has_builtin(__builtin_amdgcn_exp2f)
  return __builtin_amdgcn_exp2f(x);
#else
  return exp2f(x);
#endif
}

__device__ __forceinline__ void async_ld16(const void* g, void* l) {
  __builtin_amdgcn_global_load_lds(
      (const __attribute__((address_space(1))) unsigned int*)g,
      (__attribute__((address_space(3))) unsigned int*)l, 16, 0, 0);
}

// ---------------------------------------------------------------------------
// Fused fp32->bf16 convert for all 3 inputs.
// Segments by linear block id: [0,4096) x, [4096,7168) qkv_w, [7168,8192) o_w.
// ---------------------------------------------------------------------------
__global__ void convert_all(const float* __restrict__ x, const float* __restrict__ w,
                            const float* __restrict__ ow,
                            unsigned short* __restrict__ xb,
                            unsigned short* __restrict__ wb,
                            unsigned short* __restrict__ owb) {
  int b = blockIdx.x;
  const f32x4* src;
  u16x4* dst;
  int idx;
  if (b < 4096) {
    src = (const f32x4*)x; dst = (u16x4*)xb; idx = b * 256 + threadIdx.x;
  } else if (b < 7168) {
    src = (const f32x4*)w; dst = (u16x4*)wb; idx = (b - 4096) * 256 + threadIdx.x;
  } else {
    src = (const f32x4*)ow; dst = (u16x4*)owb; idx = (b - 7168) * 256 + threadIdx.x;
  }
  f32x4 v = src[idx];
  u16x4 r;
  r.x = f2bf(v.x); r.y = f2bf(v.y); r.z = f2bf(v.z); r.w = f2bf(v.w);
  dst[idx] = r;
}

// ---------------------------------------------------------------------------
// GEMM 1, 8-WAVE (512 threads): C[m][e] = sum_k A[m][k]*B[e][k], 128x192
// tile, BK=64. Grid 16x32 = 512 blocks = 2/CU even -> 16 waves/CU (vs 8 at
// 256 threads); staged bytes per MFMA improve 1.4x; barrier gens halve.
// col0 = bx*192 = head stride: each block maps to exactly one head.
// 8 waves in 2x4: each 64x48 via 4x3 MFMA tiles. Per-head scatter epilogue.
// ---------------------------------------------------------------------------
__global__ __launch_bounds__(512, 4) void gemm_qkv(
    const short* __restrict__ X, const short* __restrict__ W,
    unsigned short* __restrict__ qws, unsigned short* __restrict__ kws,
    unsigned short* __restrict__ vtws) {
  const int K = 1024;
  __shared__ __attribute__((aligned(16))) short As[128 * 64];
  __shared__ __attribute__((aligned(16))) short Bs[192 * 64];
  const int tid = threadIdx.x;
  const int w = tid >> 6, l = tid & 63, l15 = l & 15, quad = l >> 4;
  const int wm = (w & 1) * 64, wn = (w >> 1) * 48;
  const int row0 = blockIdx.y * 128, col0 = blockIdx.x * 192;

  f32x4 zero = {0.f, 0.f, 0.f, 0.f};
  f32x4 acc[4][3];
  for (int i = 0; i < 4; ++i)
    for (int j = 0; j < 3; ++j) acc[i][j] = zero;

  const short* Ag = X + row0 * K;
  const short* Bg = W + col0 * K;

  for (int k0 = 0; k0 < K; k0 += 64) {
    __syncthreads();
    for (int i = 0; i < 2; ++i) {
      int u = i * 512 + tid;
      int r = u >> 3, c = u & 7;
      async_ld16(Ag + r * K + k0 + c * 8, As + u * 8);
    }
    for (int i = 0; i < 3; ++i) {
      int u = i * 512 + tid;
      int r = u >> 3, c = u & 7;
      async_ld16(Bg + r * K + k0 + c * 8, Bs + u * 8);
    }
    __syncthreads();
    for (int kk = 0; kk < 2; ++kk) {
      short8 a[4], b[3];
      for (int i = 0; i < 4; ++i)
        a[i] = *(const short8*)(As + (wm + i * 16 + l15) * 64 + kk * 32 + quad * 8);
      for (int j = 0; j < 3; ++j)
        b[j] = *(const short8*)(Bs + (wn + j * 16 + l15) * 64 + kk * 32 + quad * 8);
      for (int i = 0; i < 4; ++i)
        for (int j = 0; j < 3; ++j)
          acc[i][j] = __builtin_amdgcn_mfma_f32_16x16x32_bf16(a[i], b[j], acc[i][j], 0, 0, 0);
    }
  }

  for (int i = 0; i < 4; ++i) {
    int rowb = row0 + wm + i * 16 + quad * 4;   // 4-aligned: same n for 4 rows
    int n = rowb >> 11, s = rowb & 2047;
    for (int j = 0; j < 3; ++j) {
      int e = col0 + wn + j * 16 + l15;
      int h = e / 192;
      int rem = e - h * 192;
      int part = rem >> 6, d = rem & 63;
      f32x4 v = acc[i][j];
      if (part == 0) {
        unsigned short* p = qws + ((n * H + h) * S + s) * HD + d;
        p[0] = f2bf(v.x * QSCALE);
        p[HD] = f2bf(v.y * QSCALE);
        p[2 * HD] = f2bf(v.z * QSCALE);
        p[3 * HD] = f2bf(v.w * QSCALE);
      } else if (part == 1) {
        unsigned short* p = kws + ((n * H + h) * S + s) * HD + d;
        p[0] = f2bf(v.x);
        p[HD] = f2bf(v.y);
        p[2 * HD] = f2bf(v.z);
        p[3 * HD] = f2bf(v.w);
      } else {
        u16x4 pk;
        pk.x = f2bf(v.x); pk.y = f2bf(v.y); pk.z = f2bf(v.z); pk.w = f2bf(v.w);
        *(u16x4*)(vtws + ((n * H + h) * HD + d) * S + s) = pk;
      }
    }
  }
}

// ---------------------------------------------------------------------------
// Flash attention, 8-WAVE blocks (R13-exact, 58.5us): Q-tile 128, grid
// 16x16x2 = 512 blocks = 2/CU. K/V double-buffered async DMA (gather-side
// XOR swizzle), 1 barrier/step. R9: V-direct regresses; R12: upfront vf
// reads regress. Static-max softmax in exp2 domain; per-lane sum partials;
// Pt wave-private with lgkmcnt(0) RAW ordering.
// ---------------------------------------------------------------------------
__global__ __launch_bounds__(512, 4) void flash(
    const short* __restrict__ qws, const short* __restrict__ kws,
    const short* __restrict__ vtws, unsigned short* __restrict__ vals) {
  __shared__ __attribute__((aligned(16))) short Ks[2][64 * 64];
  __shared__ __attribute__((aligned(16))) short Vts[2][64 * 64];
  __shared__ __attribute__((aligned(16))) short Pt[8][16 * 64];
  const int tid = threadIdx.x;
  const int w = tid >> 6, l = tid & 63, l15 = l & 15, quad = l >> 4;
  const int qb = blockIdx.x, h = blockIdx.y, n = blockIdx.z;
  const int nh = n * H + h;
  const short* Qh = qws + nh * S * HD;
  const short* Kh = kws + nh * S * HD;
  const short* Vth = vtws + nh * HD * S;

  const int q0 = qb * 128 + w * 16;
  short8 qf[2];
  for (int c = 0; c < 2; ++c)
    qf[c] = *(const short8*)(Qh + (q0 + l15) * HD + c * 32 + quad * 8);

  // swizzled granule offsets (shorts) for fragment reads
  const int swz0 = ((4 * 0 + quad) ^ (l15 & 7)) * 8;
  const int swz1 = ((4 * 1 + quad) ^ (l15 & 7)) * 8;

  float lpart = 0.f;                       // per-lane partial of sum(exp2(s))
  f32x4 zero = {0.f, 0.f, 0.f, 0.f};
  f32x4 oacc[4] = {zero, zero, zero, zero};

  // DMA stage of one 64-step KV tile into buffer `buf` (swizzle via gather).
  // 512 threads: exactly one 16B K-chunk + one V-chunk per thread.
  auto stage = [&](int kv0, int buf) {
    int u = tid;
    int r = u >> 3;
    int c = (u & 7) ^ (r & 7);
    async_ld16(Kh + (kv0 + r) * HD + c * 8, &Ks[buf][u * 8]);
    async_ld16(Vth + r * S + kv0 + c * 8, &Vts[buf][u * 8]);
  };

  stage(0, 0);
  for (int t = 0; t < 32; ++t) {
    const int buf = t & 1;
    __syncthreads();                       // drains DMA for tile t; frees buf^1
    if (t < 31) stage((t + 1) * 64, buf ^ 1);

    const short* Kb = Ks[buf];
    const short* Vb = Vts[buf];

    f32x4 sacc[4] = {zero, zero, zero, zero};
    {
      short8 kf[4];
      for (int i = 0; i < 4; ++i)
        kf[i] = *(const short8*)(Kb + (i * 16 + l15) * 64 + swz0);
      for (int i = 0; i < 4; ++i)
        sacc[i] = __builtin_amdgcn_mfma_f32_16x16x32_bf16(kf[i], qf[0], sacc[i], 0, 0, 0);
      for (int i = 0; i < 4; ++i)
        kf[i] = *(const short8*)(Kb + (i * 16 + l15) * 64 + swz1);
      for (int i = 0; i < 4; ++i)
        sacc[i] = __builtin_amdgcn_mfma_f32_16x16x32_bf16(kf[i], qf[1], sacc[i], 0, 0, 0);
    }

    // static-max softmax: p = 2^s; per-lane partial sum only
    for (int i = 0; i < 4; ++i) {
      f32x4 p;
      p.x = fexp2(sacc[i].x);
      p.y = fexp2(sacc[i].y);
      p.z = fexp2(sacc[i].z);
      p.w = fexp2(sacc[i].w);
      sacc[i] = p;
      lpart += p.x + p.y + p.z + p.w;
    }

    // P^T (C-layout) -> wave-private LDS [q=l15][kv], swizzled
    for (int i = 0; i < 4; ++i) {
      int g = 2 * i + (quad >> 1);
      uint2v pk;
      pk.x = pk_bf16(sacc[i].x, sacc[i].y);
      pk.y = pk_bf16(sacc[i].z, sacc[i].w);
      *(uint2v*)(&Pt[w][l15 * 64 + ((g ^ (l15 & 7)) * 8) + (quad & 1) * 4]) = pk;
    }
    asm volatile("s_waitcnt lgkmcnt(0)" ::: "memory");  // wave-private RAW order

    {
      short8 vf[4];
      short8 pf0 = *(const short8*)(&Pt[w][l15 * 64 + swz0]);
      short8 pf1 = *(const short8*)(&Pt[w][l15 * 64 + swz1]);
      for (int i = 0; i < 4; ++i)
        vf[i] = *(const short8*)(Vb + (i * 16 + l15) * 64 + swz0);
      for (int i = 0; i < 4; ++i)
        oacc[i] = __builtin_amdgcn_mfma_f32_16x16x32_bf16(vf[i], pf0, oacc[i], 0, 0, 0);
      for (int i = 0; i < 4; ++i)
        vf[i] = *(const short8*)(Vb + (i * 16 + l15) * 64 + swz1);
      for (int i = 0; i < 4; ++i)
        oacc[i] = __builtin_amdgcn_mfma_f32_16x16x32_bf16(vf[i], pf1, oacc[i], 0, 0, 0);
    }
  }

  // final row-sum across quads, then O^T[d][q] / l -> vals[n][s][h*64+d]
  float lrun = lpart;
  lrun += __shfl_xor(lrun, 16);
  lrun += __shfl_xor(lrun, 32);
  float inv = 1.0f / lrun;
  int s = q0 + l15;
  for (int i = 0; i < 4; ++i) {
    uint2v pk;
    pk.x = pk_bf16(oacc[i].x * inv, oacc[i].y * inv);
    pk.y = pk_bf16(oacc[i].z * inv, oacc[i].w * inv);
    *(uint2v*)(vals + (n * S + s) * DM + h * HD + i * 16 + quad * 4) = pk;
  }
}

// ---------------------------------------------------------------------------
// GEMM 3, 8-WAVE (512 threads): out = vals @ o_w^T, FP32 output. 128x64
// tile, grid 16x32 = 512 blocks = 2/CU -> 16 waves/CU (vs 8). 8 waves in
// 4x2: each 32x32 via 2x2 MFMA tiles.
// ---------------------------------------------------------------------------
__global__ __launch_bounds__(512, 4) void gemm_out(
    const short* __restrict__ A, const short* __restrict__ W,
    float* __restrict__ out) {
  const int K = 1024;
  __shared__ __attribute__((aligned(16))) short As[128 * 64];
  __shared__ __attribute__((aligned(16))) short Bs[64 * 64];
  const int tid = threadIdx.x;
  const int w = tid >> 6, l = tid & 63, l15 = l & 15, quad = l >> 4;
  const int wm = (w & 3) * 32, wn = (w >> 2) * 32;
  const int row0 = blockIdx.y * 128, col0 = blockIdx.x * 64;

  f32x4 zero = {0.f, 0.f, 0.f, 0.f};
  f32x4 acc[2][2];
  for (int i = 0; i < 2; ++i)
    for (int j = 0; j < 2; ++j) acc[i][j] = zero;

  const short* Ag = A + row0 * K;
  const short* Bg = W + col0 * K;

  for (int k0 = 0; k0 < K; k0 += 64) {
    __syncthreads();
    for (int i = 0; i < 2; ++i) {
      int u = i * 512 + tid;
      int r = u >> 3, c = u & 7;
      async_ld16(Ag + r * K + k0 + c * 8, As + u * 8);
    }
    {
      int u = tid;
      int r = u >> 3, c = u & 7;
      async_ld16(Bg + r * K + k0 + c * 8, Bs + u * 8);
    }
    __syncthreads();
    for (int kk = 0; kk < 2; ++kk) {
      short8 a[2], b[2];
      for (int i = 0; i < 2; ++i)
        a[i] = *(const short8*)(As + (wm + i * 16 + l15) * 64 + kk * 32 + quad * 8);
      for (int j = 0; j < 2; ++j)
        b[j] = *(const short8*)(Bs + (wn + j * 16 + l15) * 64 + kk * 32 + quad * 8);
      for (int i = 0; i < 2; ++i)
        for (int j = 0; j < 2; ++j)
          acc[i][j] = __builtin_amdgcn_mfma_f32_16x16x32_bf16(a[i], b[j], acc[i][j], 0, 0, 0);
    }
  }

  for (int i = 0; i < 2; ++i) {
    int rowb = row0 + wm + i * 16 + quad * 4;
    for (int j = 0; j < 2; ++j) {
      int e = col0 + wn + j * 16 + l15;
      f32x4 v = acc[i][j];
      out[(rowb + 0) * 1024 + e] = v.x;
      out[(rowb + 1) * 1024 + e] = v.y;
      out[(rowb + 2) * 1024 + e] = v.z;
      out[(rowb + 3) * 1024 + e] = v.w;
    }
  }
}

extern "C" void kernel_launch(void* const* d_in, const int* in_sizes, int n_in,
                              void* d_out, int out_size, void* d_ws, size_t ws_size,
                              hipStream_t stream) {
  const float* x = (const float*)d_in[0];      // (2, 2048, 1024) fp32
  const float* qkv_w = (const float*)d_in[1];  // (3072, 1024) fp32
  const float* o_w = (const float*)d_in[2];    // (1024, 1024) fp32
  float* out = (float*)d_out;                  // fp32

  char* ws = (char*)d_ws;
  unsigned short* xb   = (unsigned short*)(ws);                   // [0, 8M)
  unsigned short* wb   = (unsigned short*)(ws + (8ull << 20));    // [8M, 14M)
  unsigned short* owb  = (unsigned short*)(ws + (14ull << 20));   // [14M, 16M)
  unsigned short* qws  = (unsigned short*)(ws + (16ull << 20));   // [16M, 24M)
  unsigned short* kws  = (unsigned short*)(ws + (24ull << 20));   // [24M, 32M)
  unsigned short* vtws = (unsigned short*)(ws + (32ull << 20));   // [32M, 40M)
  unsigned short* vals = xb;  // alias: xb dead after gemm_qkv

  convert_all<<<8192, 256, 0, stream>>>(x, qkv_w, o_w, xb, wb, owb);
  gemm_qkv<<<dim3(16, 32), 512, 0, stream>>>(
      (const short*)xb, (const short*)wb, qws, kws, vtws);
  flash<<<dim3(16, 16, 2), 512, 0, stream>>>(
      (const short*)qws, (const short*)kws, (const short*)vtws, vals);
  gemm_out<<<dim3(16, 32), 512, 0, stream>>>(
      (const short*)vals, (const short*)owb, out);
}

// Round 15
// 186.364 us; speedup vs baseline: 1.0136x; 1.0136x over previous
//
#include <hip/hip_runtime.h>
#include <math.h>

#define H 16
#define S 2048
#define DM 1024
#define HD 64
// 0.125 (1/sqrt(64)) * log2(e): softmax computed in exp2 domain
#define QSCALE 0.18033688011112042f

typedef __attribute__((ext_vector_type(8))) short short8;
typedef __attribute__((ext_vector_type(4))) float f32x4;
typedef __attribute__((ext_vector_type(4))) unsigned short u16x4;
typedef __attribute__((ext_vector_type(2))) unsigned int uint2v;
#if __has_builtin(__builtin_amdgcn_cvt_pk_bf16_f32)
typedef __attribute__((ext_vector_type(2))) __bf16 bf16x2;
#endif

__device__ __forceinline__ unsigned short f2bf(float f) {
  unsigned int u = __builtin_bit_cast(unsigned int, f);
  u = (u + 0x7fffu + ((u >> 16) & 1u)) >> 16;
  return (unsigned short)u;
}

__device__ __forceinline__ unsigned int pk_bf16(float a, float b) {
#if __has_builtin(__builtin_amdgcn_cvt_pk_bf16_f32)
  bf16x2 r = __builtin_amdgcn_cvt_pk_bf16_f32(a, b);
  return __builtin_bit_cast(unsigned int, r);
#else
  return (unsigned int)f2bf(a) | ((unsigned int)f2bf(b) << 16);
#endif
}

__device__ __forceinline__ float fexp2(float x) {
#if __has_builtin(__builtin_amdgcn_exp2f)
  return __builtin_amdgcn_exp2f(x);
#else
  return exp2f(x);
#endif
}

__device__ __forceinline__ void async_ld16(const void* g, void* l) {
  __builtin_amdgcn_global_load_lds(
      (const __attribute__((address_space(1))) unsigned int*)g,
      (__attribute__((address_space(3))) unsigned int*)l, 16, 0, 0);
}

// ---------------------------------------------------------------------------
// Fused fp32->bf16 convert for all 3 inputs.
// Segments by linear block id: [0,4096) x, [4096,7168) qkv_w, [7168,8192) o_w.
// ---------------------------------------------------------------------------
__global__ void convert_all(const float* __restrict__ x, const float* __restrict__ w,
                            const float* __restrict__ ow,
                            unsigned short* __restrict__ xb,
                            unsigned short* __restrict__ wb,
                            unsigned short* __restrict__ owb) {
  int b = blockIdx.x;
  const f32x4* src;
  u16x4* dst;
  int idx;
  if (b < 4096) {
    src = (const f32x4*)x; dst = (u16x4*)xb; idx = b * 256 + threadIdx.x;
  } else if (b < 7168) {
    src = (const f32x4*)w; dst = (u16x4*)wb; idx = (b - 4096) * 256 + threadIdx.x;
  } else {
    src = (const f32x4*)ow; dst = (u16x4*)owb; idx = (b - 7168) * 256 + threadIdx.x;
  }
  f32x4 v = src[idx];
  u16x4 r;
  r.x = f2bf(v.x); r.y = f2bf(v.y); r.z = f2bf(v.z); r.w = f2bf(v.w);
  dst[idx] = r;
}

// ---------------------------------------------------------------------------
// GEMM 1 (R13-exact; R14's 8-wave variant regressed): 128x96 tile, BK=64,
// grid 32x32 = 1024 blocks, two even generations at 2/CU. 4 waves, each
// 64x48 via 4x3 MFMA tiles. Per-head scatter epilogue (Q*QSCALE, K, V^T).
// ---------------------------------------------------------------------------
__global__ __launch_bounds__(256, 2) void gemm_qkv(
    const short* __restrict__ X, const short* __restrict__ W,
    unsigned short* __restrict__ qws, unsigned short* __restrict__ kws,
    unsigned short* __restrict__ vtws) {
  const int K = 1024;
  __shared__ __attribute__((aligned(16))) short As[128 * 64];
  __shared__ __attribute__((aligned(16))) short Bs[96 * 64];
  const int tid = threadIdx.x;
  const int w = tid >> 6, l = tid & 63, l15 = l & 15, quad = l >> 4;
  const int wm = (w >> 1) * 64, wn = (w & 1) * 48;
  const int row0 = blockIdx.y * 128, col0 = blockIdx.x * 96;

  f32x4 zero = {0.f, 0.f, 0.f, 0.f};
  f32x4 acc[4][3];
  for (int i = 0; i < 4; ++i)
    for (int j = 0; j < 3; ++j) acc[i][j] = zero;

  const short* Ag = X + row0 * K;
  const short* Bg = W + col0 * K;

  for (int k0 = 0; k0 < K; k0 += 64) {
    __syncthreads();
    for (int i = 0; i < 4; ++i) {
      int u = i * 256 + tid;
      int r = u >> 3, c = u & 7;
      async_ld16(Ag + r * K + k0 + c * 8, As + u * 8);
    }
    for (int i = 0; i < 3; ++i) {
      int u = i * 256 + tid;
      int r = u >> 3, c = u & 7;
      async_ld16(Bg + r * K + k0 + c * 8, Bs + u * 8);
    }
    __syncthreads();
    for (int kk = 0; kk < 2; ++kk) {
      short8 a[4], b[3];
      for (int i = 0; i < 4; ++i)
        a[i] = *(const short8*)(As + (wm + i * 16 + l15) * 64 + kk * 32 + quad * 8);
      for (int j = 0; j < 3; ++j)
        b[j] = *(const short8*)(Bs + (wn + j * 16 + l15) * 64 + kk * 32 + quad * 8);
      for (int i = 0; i < 4; ++i)
        for (int j = 0; j < 3; ++j)
          acc[i][j] = __builtin_amdgcn_mfma_f32_16x16x32_bf16(a[i], b[j], acc[i][j], 0, 0, 0);
    }
  }

  for (int i = 0; i < 4; ++i) {
    int rowb = row0 + wm + i * 16 + quad * 4;   // 4-aligned: same n for 4 rows
    int n = rowb >> 11, s = rowb & 2047;
    for (int j = 0; j < 3; ++j) {
      int e = col0 + wn + j * 16 + l15;
      int h = e / 192;
      int rem = e - h * 192;
      int part = rem >> 6, d = rem & 63;
      f32x4 v = acc[i][j];
      if (part == 0) {
        unsigned short* p = qws + ((n * H + h) * S + s) * HD + d;
        p[0] = f2bf(v.x * QSCALE);
        p[HD] = f2bf(v.y * QSCALE);
        p[2 * HD] = f2bf(v.z * QSCALE);
        p[3 * HD] = f2bf(v.w * QSCALE);
      } else if (part == 1) {
        unsigned short* p = kws + ((n * H + h) * S + s) * HD + d;
        p[0] = f2bf(v.x);
        p[HD] = f2bf(v.y);
        p[2 * HD] = f2bf(v.z);
        p[3 * HD] = f2bf(v.w);
      } else {
        u16x4 pk;
        pk.x = f2bf(v.x); pk.y = f2bf(v.y); pk.z = f2bf(v.z); pk.w = f2bf(v.w);
        *(u16x4*)(vtws + ((n * H + h) * HD + d) * S + s) = pk;
      }
    }
  }
}

// ---------------------------------------------------------------------------
// Flash attention, 8-wave blocks, Q-tile 128, KV-STEP 128 (2 sub-steps per
// barrier): barrier/drain count 32->16 for the same MFMA work — the R13 win
// mechanism applied again. LDS 80KB = exactly 2 blocks/CU (matches grid cap
// 512 blocks = 2/CU). K staged as 128 swizzled rows; V as two 64-kv
// sub-tiles (staging stays lane-affine for global_load_lds). Inner body per
// sub-step is R13-exact (R9: V-direct regresses; R12: upfront vf regresses).
// Static-max softmax in exp2 domain; per-lane sum partials; Pt wave-private
// with lgkmcnt(0) RAW ordering (same-wave DS FIFO orders ss=0 reads before
// ss=1 writes).
// ---------------------------------------------------------------------------
__global__ __launch_bounds__(512, 4) void flash(
    const short* __restrict__ qws, const short* __restrict__ kws,
    const short* __restrict__ vtws, unsigned short* __restrict__ vals) {
  __shared__ __attribute__((aligned(16))) short Ks[2][128 * 64];
  __shared__ __attribute__((aligned(16))) short Vts[2][2][64 * 64];
  __shared__ __attribute__((aligned(16))) short Pt[8][16 * 64];
  const int tid = threadIdx.x;
  const int w = tid >> 6, l = tid & 63, l15 = l & 15, quad = l >> 4;
  const int qb = blockIdx.x, h = blockIdx.y, n = blockIdx.z;
  const int nh = n * H + h;
  const short* Qh = qws + nh * S * HD;
  const short* Kh = kws + nh * S * HD;
  const short* Vth = vtws + nh * HD * S;

  const int q0 = qb * 128 + w * 16;
  short8 qf[2];
  for (int c = 0; c < 2; ++c)
    qf[c] = *(const short8*)(Qh + (q0 + l15) * HD + c * 32 + quad * 8);

  // swizzled granule offsets (shorts) for fragment reads
  const int swz0 = ((4 * 0 + quad) ^ (l15 & 7)) * 8;
  const int swz1 = ((4 * 1 + quad) ^ (l15 & 7)) * 8;

  float lpart = 0.f;                       // per-lane partial of sum(exp2(s))
  f32x4 zero = {0.f, 0.f, 0.f, 0.f};
  f32x4 oacc[4] = {zero, zero, zero, zero};

  // DMA stage of one 128-step KV tile into buffer `buf` (swizzle via gather).
  // 512 threads x 2 chunks each for K (128 rows) and V (2x 64-kv sub-tiles).
  auto stage = [&](int kv0, int buf) {
    for (int i = 0; i < 2; ++i) {
      int u = i * 512 + tid;
      int r = u >> 3;
      int c = (u & 7) ^ (r & 7);
      async_ld16(Kh + (kv0 + r) * HD + c * 8, &Ks[buf][u * 8]);
    }
    for (int i = 0; i < 2; ++i) {
      int v = tid;                         // within-sub-tile chunk id
      int r = v >> 3;                      // d-row 0..63
      int c = (v & 7) ^ (r & 7);
      async_ld16(Vth + r * S + kv0 + i * 64 + c * 8, &Vts[buf][i][v * 8]);
    }
  };

  stage(0, 0);
  for (int t = 0; t < 16; ++t) {
    const int buf = t & 1;
    __syncthreads();                       // drains DMA for tile t; frees buf^1
    if (t < 15) stage((t + 1) * 128, buf ^ 1);

    for (int ss = 0; ss < 2; ++ss) {
      const short* Kb = &Ks[buf][ss * 64 * 64];
      const short* Vb = Vts[buf][ss];

      f32x4 sacc[4] = {zero, zero, zero, zero};
      {
        short8 kf[4];
        for (int i = 0; i < 4; ++i)
          kf[i] = *(const short8*)(Kb + (i * 16 + l15) * 64 + swz0);
        for (int i = 0; i < 4; ++i)
          sacc[i] = __builtin_amdgcn_mfma_f32_16x16x32_bf16(kf[i], qf[0], sacc[i], 0, 0, 0);
        for (int i = 0; i < 4; ++i)
          kf[i] = *(const short8*)(Kb + (i * 16 + l15) * 64 + swz1);
        for (int i = 0; i < 4; ++i)
          sacc[i] = __builtin_amdgcn_mfma_f32_16x16x32_bf16(kf[i], qf[1], sacc[i], 0, 0, 0);
      }

      // static-max softmax: p = 2^s; per-lane partial sum only
      for (int i = 0; i < 4; ++i) {
        f32x4 p;
        p.x = fexp2(sacc[i].x);
        p.y = fexp2(sacc[i].y);
        p.z = fexp2(sacc[i].z);
        p.w = fexp2(sacc[i].w);
        sacc[i] = p;
        lpart += p.x + p.y + p.z + p.w;
      }

      // P^T (C-layout) -> wave-private LDS [q=l15][kv], swizzled
      for (int i = 0; i < 4; ++i) {
        int g = 2 * i + (quad >> 1);
        uint2v pk;
        pk.x = pk_bf16(sacc[i].x, sacc[i].y);
        pk.y = pk_bf16(sacc[i].z, sacc[i].w);
        *(uint2v*)(&Pt[w][l15 * 64 + ((g ^ (l15 & 7)) * 8) + (quad & 1) * 4]) = pk;
      }
      asm volatile("s_waitcnt lgkmcnt(0)" ::: "memory");  // wave-private RAW

      {
        short8 vf[4];
        short8 pf0 = *(const short8*)(&Pt[w][l15 * 64 + swz0]);
        short8 pf1 = *(const short8*)(&Pt[w][l15 * 64 + swz1]);
        for (int i = 0; i < 4; ++i)
          vf[i] = *(const short8*)(Vb + (i * 16 + l15) * 64 + swz0);
        for (int i = 0; i < 4; ++i)
          oacc[i] = __builtin_amdgcn_mfma_f32_16x16x32_bf16(vf[i], pf0, oacc[i], 0, 0, 0);
        for (int i = 0; i < 4; ++i)
          vf[i] = *(const short8*)(Vb + (i * 16 + l15) * 64 + swz1);
        for (int i = 0; i < 4; ++i)
          oacc[i] = __builtin_amdgcn_mfma_f32_16x16x32_bf16(vf[i], pf1, oacc[i], 0, 0, 0);
      }
    }
  }

  // final row-sum across quads, then O^T[d][q] / l -> vals[n][s][h*64+d]
  float lrun = lpart;
  lrun += __shfl_xor(lrun, 16);
  lrun += __shfl_xor(lrun, 32);
  float inv = 1.0f / lrun;
  int s = q0 + l15;
  for (int i = 0; i < 4; ++i) {
    uint2v pk;
    pk.x = pk_bf16(oacc[i].x * inv, oacc[i].y * inv);
    pk.y = pk_bf16(oacc[i].z * inv, oacc[i].w * inv);
    *(uint2v*)(vals + (n * S + s) * DM + h * HD + i * 16 + quad * 4) = pk;
  }
}

// ---------------------------------------------------------------------------
// GEMM 3 (R13-exact): out = vals @ o_w^T, FP32 output. 128x64 tile, grid
// 16x32 = 512 blocks = 2/CU. 4 waves, each 64x32 via 4x2 MFMA tiles.
// ---------------------------------------------------------------------------
__global__ __launch_bounds__(256, 2) void gemm_out(
    const short* __restrict__ A, const short* __restrict__ W,
    float* __restrict__ out) {
  const int K = 1024;
  __shared__ __attribute__((aligned(16))) short As[128 * 64];
  __shared__ __attribute__((aligned(16))) short Bs[64 * 64];
  const int tid = threadIdx.x;
  const int w = tid >> 6, l = tid & 63, l15 = l & 15, quad = l >> 4;
  const int wm = (w >> 1) * 64, wn = (w & 1) * 32;
  const int row0 = blockIdx.y * 128, col0 = blockIdx.x * 64;

  f32x4 zero = {0.f, 0.f, 0.f, 0.f};
  f32x4 acc[4][2];
  for (int i = 0; i < 4; ++i)
    for (int j = 0; j < 2; ++j) acc[i][j] = zero;

  const short* Ag = A + row0 * K;
  const short* Bg = W + col0 * K;

  for (int k0 = 0; k0 < K; k0 += 64) {
    __syncthreads();
    for (int i = 0; i < 4; ++i) {
      int u = i * 256 + tid;
      int r = u >> 3, c = u & 7;
      async_ld16(Ag + r * K + k0 + c * 8, As + u * 8);
    }
    for (int i = 0; i < 2; ++i) {
      int u = i * 256 + tid;
      int r = u >> 3, c = u & 7;
      async_ld16(Bg + r * K + k0 + c * 8, Bs + u * 8);
    }
    __syncthreads();
    for (int kk = 0; kk < 2; ++kk) {
      short8 a[4], b[2];
      for (int i = 0; i < 4; ++i)
        a[i] = *(const short8*)(As + (wm + i * 16 + l15) * 64 + kk * 32 + quad * 8);
      for (int j = 0; j < 2; ++j)
        b[j] = *(const short8*)(Bs + (wn + j * 16 + l15) * 64 + kk * 32 + quad * 8);
      for (int i = 0; i < 4; ++i)
        for (int j = 0; j < 2; ++j)
          acc[i][j] = __builtin_amdgcn_mfma_f32_16x16x32_bf16(a[i], b[j], acc[i][j], 0, 0, 0);
    }
  }

  for (int i = 0; i < 4; ++i) {
    int rowb = row0 + wm + i * 16 + quad * 4;
    for (int j = 0; j < 2; ++j) {
      int e = col0 + wn + j * 16 + l15;
      f32x4 v = acc[i][j];
      out[(rowb + 0) * 1024 + e] = v.x;
      out[(rowb + 1) * 1024 + e] = v.y;
      out[(rowb + 2) * 1024 + e] = v.z;
      out[(rowb + 3) * 1024 + e] = v.w;
    }
  }
}

extern "C" void kernel_launch(void* const* d_in, const int* in_sizes, int n_in,
                              void* d_out, int out_size, void* d_ws, size_t ws_size,
                              hipStream_t stream) {
  const float* x = (const float*)d_in[0];      // (2, 2048, 1024) fp32
  const float* qkv_w = (const float*)d_in[1];  // (3072, 1024) fp32
  const float* o_w = (const float*)d_in[2];    // (1024, 1024) fp32
  float* out = (float*)d_out;                  // fp32

  char* ws = (char*)d_ws;
  unsigned short* xb   = (unsigned short*)(ws);                   // [0, 8M)
  unsigned short* wb   = (unsigned short*)(ws + (8ull << 20));    // [8M, 14M)
  unsigned short* owb  = (unsigned short*)(ws + (14ull << 20));   // [14M, 16M)
  unsigned short* qws  = (unsigned short*)(ws + (16ull << 20));   // [16M, 24M)
  unsigned short* kws  = (unsigned short*)(ws + (24ull << 20));   // [24M, 32M)
  unsigned short* vtws = (unsigned short*)(ws + (32ull << 20));   // [32M, 40M)
  unsigned short* vals = xb;  // alias: xb dead after gemm_qkv

  convert_all<<<8192, 256, 0, stream>>>(x, qkv_w, o_w, xb, wb, owb);
  gemm_qkv<<<dim3(32, 32), 256, 0, stream>>>(
      (const short*)xb, (const short*)wb, qws, kws, vtws);
  flash<<<dim3(16, 16, 2), 512, 0, stream>>>(
      (const short*)qws, (const short*)kws, (const short*)vtws, vals);
  gemm_out<<<dim3(16, 32), 256, 0, stream>>>(
      (const short*)vals, (const short*)owb, out);
}